// Round 9
// baseline (54.747 us; speedup 1.0000x reference)
//
#include <hip/hip_runtime.h>
#include <hip/hip_bf16.h>

// Problem constants
#define B_DIM   32768
#define A_DIM   64
#define L_DIM   1024          // K
#define N_COLS  128           // 2*A

using bf16x8 = __attribute__((ext_vector_type(8))) __bf16;
using f32x4  = __attribute__((ext_vector_type(4))) float;

// global -> LDS direct (16B per lane; LDS dest = wave-uniform base + lane*16)
#define GLL16(g, l)                                                            \
    __builtin_amdgcn_global_load_lds(                                          \
        (const __attribute__((address_space(1))) unsigned int*)(g),            \
        (__attribute__((address_space(3))) unsigned int*)(l), 16, 0, 0)

// ---------------------------------------------------------------------------
// Pre-kernel: convert W [128 x 1024] f32 -> bf16 in MFMA B-fragment order.
// Unit v (16B): nl=v&15, sub=(v>>4)&3, cf=(v>>6)&7, ks=(v>>9)&31
//   holds Wm[n = cf*16+nl][k = ks*32 + sub*8 + i], i=0..7
// Chunk ch (K=64, ksteps 2ch,2ch+1) = units [ch*1024, (ch+1)*1024) contiguous.
// ---------------------------------------------------------------------------
__global__ __launch_bounds__(256)
void convert_w_kernel(const float* __restrict__ W, bf16x8* __restrict__ ws) {
    int v   = blockIdx.x * 256 + threadIdx.x;   // 0..16383
    int nl  = v & 15;
    int sub = (v >> 4) & 3;
    int cf  = (v >> 6) & 7;
    int ks  = (v >> 9) & 31;
    int n   = cf * 16 + nl;
    int k   = ks * 32 + sub * 8;
    const float4* wp = (const float4*)(W + (size_t)n * L_DIM + k);
    float4 w0 = wp[0];
    float4 w1 = wp[1];
    bf16x8 u;
    u[0] = (__bf16)w0.x; u[1] = (__bf16)w0.y;
    u[2] = (__bf16)w0.z; u[3] = (__bf16)w0.w;
    u[4] = (__bf16)w1.x; u[5] = (__bf16)w1.y;
    u[6] = (__bf16)w1.z; u[7] = (__bf16)w1.w;
    ws[v] = u;
}

__device__ __forceinline__ bf16x8 cvt8(float4 a, float4 b) {
    bf16x8 u;
    u[0] = (__bf16)a.x; u[1] = (__bf16)a.y; u[2] = (__bf16)a.z; u[3] = (__bf16)a.w;
    u[4] = (__bf16)b.x; u[5] = (__bf16)b.y; u[6] = (__bf16)b.z; u[7] = (__bf16)b.w;
    return u;
}

// ---------------------------------------------------------------------------
// Main kernel (many-blocks / TLP): 256 threads = 4 waves; wave (r,c2) owns
// rows [blk*32 + r*16, +16) x cols [c2*64, +64)  (acc = 4 x f32x4 = 16 VGPR).
// Grid = 1024 -> 4 blocks/CU -> 16 waves/CU (4/SIMD): latency hidden by TLP
// of independent blocks (fillBuffer reaches 87% peak at ~3 waves/SIMD).
// B: fragment-ordered ws, staged per K=64 chunk (16 KB) via global_load_lds,
// double-buffered (32 KB LDS). All LDS traffic lane-contiguous, 0 conflicts.
// A: JIT global->reg (twin col-wave re-reads hit L1). 17 barriers/block,
// drains staggered across the 4 resident blocks.
// ---------------------------------------------------------------------------
__global__ __launch_bounds__(256, 4)
void branched_policy_kernel(const float* __restrict__ F,
                            const float4* __restrict__ Wf,
                            const float* __restrict__ bias,
                            float* __restrict__ out) {
    __shared__ float4 ldsB[2][1024];   // 2 x 16 KB chunks

    const int tid  = threadIdx.x;
    const int lane = tid & 63;
    const int wave = tid >> 6;        // 0..3
    const int r    = wave >> 1;       // row-tile 0/1
    const int c2   = wave & 1;        // col-half 0/1
    const int lcol = lane & 15;       // fragment row (A) / col (B)
    const int lsub = lane >> 4;       // k subgroup 0..3
    const int blk  = blockIdx.x;

    const float* fp = F + (size_t)(blk * 32 + r * 16 + lcol) * L_DIM
                        + lsub * 8;

    f32x4 acc[4];
    #pragma unroll
    for (int c = 0; c < 4; ++c) acc[c] = (f32x4){0.f, 0.f, 0.f, 0.f};

    // ---- stage chunk 0 ----
    #pragma unroll
    for (int i = 0; i < 4; ++i)
        GLL16(Wf + i * 256 + tid, &ldsB[0][i * 256 + tid]);
    __syncthreads();

    #pragma unroll 2
    for (int ch = 0; ch < 16; ++ch) {
        // issue next chunk's staging (in flight during this chunk's compute)
        if (ch + 1 < 16) {
            const float4* src = Wf + (size_t)(ch + 1) * 1024;
            #pragma unroll
            for (int i = 0; i < 4; ++i)
                GLL16(src + i * 256 + tid, &ldsB[(ch + 1) & 1][i * 256 + tid]);
        }

        // compute 2 k-steps of chunk ch
        #pragma unroll
        for (int jj = 0; jj < 2; ++jj) {
            int kk = ch * 2 + jj;
            float4 a0 = *(const float4*)(fp + kk * 32);
            float4 a1 = *(const float4*)(fp + kk * 32 + 4);
            bf16x8 af = cvt8(a0, a1);
            #pragma unroll
            for (int c = 0; c < 4; ++c) {
                int cf = c2 * 4 + c;
                bf16x8 bf = *(const bf16x8*)&ldsB[ch & 1][jj * 512 + cf * 64 + lane];
                acc[c] = __builtin_amdgcn_mfma_f32_16x16x32_bf16(af, bf, acc[c], 0, 0, 0);
            }
        }
        __syncthreads();   // next chunk arrived (vmcnt drain); buf reuse safe
    }

    // ---- epilogue: bias + tanh + de-interleave ----
    const int row0 = blk * 32 + r * 16 + lsub * 4;
    float* out0 = out;
    float* out1 = out + (size_t)B_DIM * A_DIM;
    #pragma unroll
    for (int c = 0; c < 4; ++c) {
        int   n  = (c2 * 4 + c) * 16 + lcol;
        float bv = bias[n];
        float* ob = ((n & 1) ? out1 : out0) + (n >> 1);
        #pragma unroll
        for (int j = 0; j < 4; ++j) {
            float x = acc[c][j] + bv;
            float e = __expf(2.0f * x);               // tanh = 1 - 2/(e^2x+1)
            ob[(size_t)(row0 + j) * A_DIM] = 1.0f - 2.0f / (e + 1.0f);
        }
    }
}

// ---------------------------------------------------------------------------
// Fallback (v1-style, self-contained) if ws is too small.
// ---------------------------------------------------------------------------
__global__ __launch_bounds__(256, 2)
void fallback_kernel(const float* __restrict__ F,
                     const float* __restrict__ W,
                     const float* __restrict__ bias,
                     float* __restrict__ out) {
    __shared__ bf16x8 ldsB[4096];
    const int tid  = threadIdx.x;
    const int lane = tid & 63;
    const int wave = tid >> 6;
    const int blk  = blockIdx.x;
    const int lcol = lane & 15;
    const int lsub = lane >> 4;
    const int arow = blk * 64 + wave * 16 + lcol;
    const float* Fp = F + (size_t)arow * L_DIM + lsub * 8;

    f32x4 acc[8];
    #pragma unroll
    for (int c = 0; c < 8; ++c) acc[c] = (f32x4){0.f, 0.f, 0.f, 0.f};

    for (int ch = 0; ch < 4; ++ch) {
        __syncthreads();
        #pragma unroll
        for (int i = 0; i < 16; ++i) {
            int v   = i * 256 + tid;
            int nl  = v & 15;
            int sub = (v >> 4) & 3;
            int c   = (v >> 6) & 7;
            int ks  = (v >> 9) & 7;
            int nn  = c * 16 + nl;
            int k   = ch * 256 + ks * 32 + sub * 8;
            const float4* wp = (const float4*)(W + (size_t)nn * L_DIM + k);
            ldsB[v] = cvt8(wp[0], wp[1]);
        }
        __syncthreads();
        #pragma unroll
        for (int ks = 0; ks < 8; ++ks) {
            const float4* ap = (const float4*)(Fp + ch * 256 + ks * 32);
            bf16x8 af = cvt8(ap[0], ap[1]);
            #pragma unroll
            for (int c = 0; c < 8; ++c) {
                bf16x8 bf = ldsB[(ks * 8 + c) * 64 + lane];
                acc[c] = __builtin_amdgcn_mfma_f32_16x16x32_bf16(af, bf, acc[c], 0, 0, 0);
            }
        }
    }

    const int orow0 = blk * 64 + wave * 16 + lsub * 4;
    float* out0 = out;
    float* out1 = out + (size_t)B_DIM * A_DIM;
    #pragma unroll
    for (int c = 0; c < 8; ++c) {
        int   nn  = c * 16 + lcol;
        float bvv = bias[nn];
        float* ob = (nn & 1) ? out1 : out0;
        #pragma unroll
        for (int j = 0; j < 4; ++j) {
            float x = acc[c][j] + bvv;
            float e = __expf(2.0f * x);
            ob[(size_t)(orow0 + j) * A_DIM + (nn >> 1)] = 1.0f - 2.0f / (e + 1.0f);
        }
    }
}

extern "C" void kernel_launch(void* const* d_in, const int* in_sizes, int n_in,
                              void* d_out, int out_size, void* d_ws, size_t ws_size,
                              hipStream_t stream) {
    const float* F    = (const float*)d_in[0];  // [32768, 1024] f32
    const float* W    = (const float*)d_in[1];  // [64, 2, 1024] f32
    const float* bias = (const float*)d_in[2];  // [64, 2] f32
    float* outp       = (float*)d_out;          // [2][32768, 64] f32

    const size_t ws_needed = (size_t)N_COLS * L_DIM * sizeof(__bf16);  // 256 KB

    if (ws_size >= ws_needed) {
        bf16x8* wf = (bf16x8*)d_ws;
        hipLaunchKernelGGL(convert_w_kernel, dim3(64), dim3(256), 0, stream, W, wf);
        hipLaunchKernelGGL(branched_policy_kernel, dim3(B_DIM / 32), dim3(256), 0, stream,
                           F, (const float4*)wf, bias, outp);
    } else {
        hipLaunchKernelGGL(fallback_kernel, dim3(B_DIM / 64), dim3(256), 0, stream,
                           F, W, bias, outp);
    }
}

// Round 10
// 42.961 us; speedup vs baseline: 1.2743x; 1.2743x over previous
//
#include <hip/hip_runtime.h>
#include <hip/hip_bf16.h>

// Problem constants
#define B_DIM   32768
#define A_DIM   64
#define L_DIM   1024          // K
#define N_COLS  128           // 2*A

using bf16x8 = __attribute__((ext_vector_type(8))) __bf16;
using f32x4  = __attribute__((ext_vector_type(4))) float;

// global -> LDS direct (16B per lane; LDS dest = wave-uniform base + lane*16)
#define GLL16(g, l)                                                            \
    __builtin_amdgcn_global_load_lds(                                          \
        (const __attribute__((address_space(1))) unsigned int*)(g),            \
        (__attribute__((address_space(3))) unsigned int*)(l), 16, 0, 0)

#define VM_WAIT(n)                                                             \
    asm volatile("s_waitcnt vmcnt(" #n ")" ::: "memory");                      \
    __builtin_amdgcn_sched_barrier(0)

#define LGKM_FENCE                                                             \
    asm volatile("s_waitcnt lgkmcnt(0)" ::: "memory");                         \
    __builtin_amdgcn_sched_barrier(0)

// ---------------------------------------------------------------------------
// Pre-kernel: convert W [128 x 1024] f32 -> bf16 in MFMA B-fragment order.
// Unit v (16B): nl=v&15, sub=(v>>4)&3, cf=(v>>6)&7, ks=(v>>9)&31
//   holds Wm[n = cf*16+nl][k = ks*32 + sub*8 + i], i=0..7
// Quarter Q = ksteps [Q*8,(Q+1)*8) = units [Q*4096,(Q+1)*4096), contiguous.
// ---------------------------------------------------------------------------
__global__ __launch_bounds__(256)
void convert_w_kernel(const float* __restrict__ W, bf16x8* __restrict__ ws) {
    int v   = blockIdx.x * 256 + threadIdx.x;   // 0..16383
    int nl  = v & 15;
    int sub = (v >> 4) & 3;
    int cf  = (v >> 6) & 7;
    int ks  = (v >> 9) & 31;
    int n   = cf * 16 + nl;
    int k   = ks * 32 + sub * 8;
    const float4* wp = (const float4*)(W + (size_t)n * L_DIM + k);
    float4 w0 = wp[0];
    float4 w1 = wp[1];
    bf16x8 u;
    u[0] = (__bf16)w0.x; u[1] = (__bf16)w0.y;
    u[2] = (__bf16)w0.z; u[3] = (__bf16)w0.w;
    u[4] = (__bf16)w1.x; u[5] = (__bf16)w1.y;
    u[6] = (__bf16)w1.z; u[7] = (__bf16)w1.w;
    ws[v] = u;
}

__device__ __forceinline__ bf16x8 cvt8(float4 a, float4 b) {
    bf16x8 u;
    u[0] = (__bf16)a.x; u[1] = (__bf16)a.y; u[2] = (__bf16)a.z; u[3] = (__bf16)a.w;
    u[4] = (__bf16)b.x; u[5] = (__bf16)b.y; u[6] = (__bf16)b.z; u[7] = (__bf16)b.w;
    return u;
}

// ---------------------------------------------------------------------------
// Main kernel: 256 threads = 4 waves; wave owns 32 rows (2 A-frags) x all
// 128 cols; block = 128 rows; grid = 256 = 1 block/CU.
//
// B: quarter-K (8 ksteps, 64 KB) in shared LDS, GLL-staged, restaged at
//    ch = 4/8/12 (the only barriers).
// A: per-wave private LDS double-buffer (2 x 8 KB; chunk = 2 ksteps),
//    GLL-staged with per-lane pre-swizzled global source into fragment
//    order; hand-counted s_waitcnt vmcnt(8) -> A stream never drains in
//    the steady state (compiler cannot sink GLL: no dest register).
//
// A-chunk layout (8 KB): sub-block (j,f) 2KB at (j*2+f)*2048; within:
//   GLL instr m (0/1): lane = p*16+r -> off m*1024 + p*256 + r*16 holds
//   F[row0+f*16+r][kk*32 + m*16 + p*4 .. +4)  (f32)
// Read (lane: r=lcol, p'=lsub): off1 = p'*512 + r*16, off2 = off1+256
//   -> 8 consecutive f32 of its row; both b128 reads conflict-free
//   (each 16-lane quarter covers a contiguous 256B span).
// ---------------------------------------------------------------------------
__global__ __launch_bounds__(256, 1)
void branched_policy_kernel(const float* __restrict__ F,
                            const float4* __restrict__ Wf,
                            const float* __restrict__ bias,
                            float* __restrict__ out) {
    __shared__ float4 ldsB[4096];        // 64 KB: current B quarter
    __shared__ float4 ldsA[4][2][512];   // 4 waves x 2 bufs x 8 KB

    const int tid  = threadIdx.x;
    const int lane = tid & 63;
    const int wave = tid >> 6;        // 0..3
    const int blk  = blockIdx.x;
    const int lcol = lane & 15;       // fragment row (A) / col (B)
    const int lsub = lane >> 4;       // k subgroup 0..3

    const int row0 = blk * 128 + wave * 32;

    // per-lane GLL source base (instr (j,f,m) adds kk*32 + m*16)
    const float* fsrc0 = F + (size_t)(row0 + lcol) * L_DIM + lsub * 4;
    const float* fsrc1 = fsrc0 + 16 * L_DIM;

#define ISSUE_A(CH, BUF)                                                       \
    {                                                                          \
        _Pragma("unroll") for (int j = 0; j < 2; ++j) {                        \
            _Pragma("unroll") for (int m = 0; m < 2; ++m) {                    \
                GLL16(fsrc0 + ((CH) * 2 + j) * 32 + m * 16,                    \
                      &ldsA[wave][BUF][(j * 2 + 0) * 128 + m * 64 + lane]);    \
                GLL16(fsrc1 + ((CH) * 2 + j) * 32 + m * 16,                    \
                      &ldsA[wave][BUF][(j * 2 + 1) * 128 + m * 64 + lane]);    \
            }                                                                  \
        }                                                                      \
    }

#define ISSUE_B(Q)                                                            \
    {                                                                          \
        _Pragma("unroll") for (int i = 0; i < 16; ++i)                         \
            GLL16(Wf + (Q) * 4096 + i * 256 + tid, &ldsB[i * 256 + tid]);      \
    }

    f32x4 acc[2][8];
    #pragma unroll
    for (int f = 0; f < 2; ++f)
        #pragma unroll
        for (int cf = 0; cf < 8; ++cf)
            acc[f][cf] = (f32x4){0.f, 0.f, 0.f, 0.f};

    // ---- prologue ----
    ISSUE_A(0, 0);
    ISSUE_B(0);
    __syncthreads();                   // drains all; A(0)+B(0) resident

    #pragma unroll
    for (int ch = 0; ch < 16; ++ch) {
        if (ch == 4 || ch == 8 || ch == 12) {
            __syncthreads();           // all waves done with prev B quarter
            ISSUE_B(ch >> 2);
            __syncthreads();           // B quarter arrived (drains A too)
        }

        if (ch + 1 < 16) {
            LGKM_FENCE;                // prev ds_reads retired before overwrite
            ISSUE_A(ch + 1, (ch + 1) & 1);
            VM_WAIT(8);                // A(ch) done; A(ch+1) stays in flight
        } else {
            VM_WAIT(0);
        }

        const float4* ab = &ldsA[wave][ch & 1][0];
        #pragma unroll
        for (int j = 0; j < 2; ++j) {
            const int kk = ch * 2 + j;
            // A fragments (f32 -> bf16)
            float4 a00 = ab[(j * 2 + 0) * 128 + lsub * 32 + lcol];
            float4 a01 = ab[(j * 2 + 0) * 128 + lsub * 32 + lcol + 16];
            float4 a10 = ab[(j * 2 + 1) * 128 + lsub * 32 + lcol];
            float4 a11 = ab[(j * 2 + 1) * 128 + lsub * 32 + lcol + 16];
            bf16x8 af0 = cvt8(a00, a01);
            bf16x8 af1 = cvt8(a10, a11);
            #pragma unroll
            for (int cf = 0; cf < 8; ++cf) {
                bf16x8 bf = *(const bf16x8*)&ldsB[((kk & 7) * 8 + cf) * 64 + lane];
                acc[0][cf] = __builtin_amdgcn_mfma_f32_16x16x32_bf16(af0, bf, acc[0][cf], 0, 0, 0);
                acc[1][cf] = __builtin_amdgcn_mfma_f32_16x16x32_bf16(af1, bf, acc[1][cf], 0, 0, 0);
            }
        }
    }

    // ---- epilogue: bias + tanh + de-interleave ----
    float* out0 = out;
    float* out1 = out + (size_t)B_DIM * A_DIM;
    #pragma unroll
    for (int f = 0; f < 2; ++f) {
        const int rowb = row0 + f * 16 + lsub * 4;
        #pragma unroll
        for (int cf = 0; cf < 8; ++cf) {
            int   n  = cf * 16 + lcol;
            float bv = bias[n];
            float* ob = ((n & 1) ? out1 : out0) + (n >> 1);
            #pragma unroll
            for (int j = 0; j < 4; ++j) {
                float x = acc[f][cf][j] + bv;
                float e = __expf(2.0f * x);           // tanh = 1 - 2/(e^2x+1)
                ob[(size_t)(rowb + j) * A_DIM] = 1.0f - 2.0f / (e + 1.0f);
            }
        }
    }
#undef ISSUE_A
#undef ISSUE_B
}

// ---------------------------------------------------------------------------
// Fallback (v1-style, self-contained) if ws is too small.
// ---------------------------------------------------------------------------
__global__ __launch_bounds__(256, 2)
void fallback_kernel(const float* __restrict__ F,
                     const float* __restrict__ W,
                     const float* __restrict__ bias,
                     float* __restrict__ out) {
    __shared__ bf16x8 ldsB[4096];
    const int tid  = threadIdx.x;
    const int lane = tid & 63;
    const int wave = tid >> 6;
    const int blk  = blockIdx.x;
    const int lcol = lane & 15;
    const int lsub = lane >> 4;
    const int arow = blk * 64 + wave * 16 + lcol;
    const float* Fp = F + (size_t)arow * L_DIM + lsub * 8;

    f32x4 acc[8];
    #pragma unroll
    for (int c = 0; c < 8; ++c) acc[c] = (f32x4){0.f, 0.f, 0.f, 0.f};

    for (int ch = 0; ch < 4; ++ch) {
        __syncthreads();
        #pragma unroll
        for (int i = 0; i < 16; ++i) {
            int v   = i * 256 + tid;
            int nl  = v & 15;
            int sub = (v >> 4) & 3;
            int c   = (v >> 6) & 7;
            int ks  = (v >> 9) & 7;
            int nn  = c * 16 + nl;
            int k   = ch * 256 + ks * 32 + sub * 8;
            const float4* wp = (const float4*)(W + (size_t)nn * L_DIM + k);
            ldsB[v] = cvt8(wp[0], wp[1]);
        }
        __syncthreads();
        #pragma unroll
        for (int ks = 0; ks < 8; ++ks) {
            const float4* ap = (const float4*)(Fp + ch * 256 + ks * 32);
            bf16x8 af = cvt8(ap[0], ap[1]);
            #pragma unroll
            for (int c = 0; c < 8; ++c) {
                bf16x8 bf = ldsB[(ks * 8 + c) * 64 + lane];
                acc[c] = __builtin_amdgcn_mfma_f32_16x16x32_bf16(af, bf, acc[c], 0, 0, 0);
            }
        }
    }

    const int orow0 = blk * 64 + wave * 16 + lsub * 4;
    float* out0 = out;
    float* out1 = out + (size_t)B_DIM * A_DIM;
    #pragma unroll
    for (int c = 0; c < 8; ++c) {
        int   nn  = c * 16 + lcol;
        float bvv = bias[nn];
        float* ob = (nn & 1) ? out1 : out0;
        #pragma unroll
        for (int j = 0; j < 4; ++j) {
            float x = acc[c][j] + bvv;
            float e = __expf(2.0f * x);
            ob[(size_t)(orow0 + j) * A_DIM + (nn >> 1)] = 1.0f - 2.0f / (e + 1.0f);
        }
    }
}

extern "C" void kernel_launch(void* const* d_in, const int* in_sizes, int n_in,
                              void* d_out, int out_size, void* d_ws, size_t ws_size,
                              hipStream_t stream) {
    const float* F    = (const float*)d_in[0];  // [32768, 1024] f32
    const float* W    = (const float*)d_in[1];  // [64, 2, 1024] f32
    const float* bias = (const float*)d_in[2];  // [64, 2] f32
    float* outp       = (float*)d_out;          // [2][32768, 64] f32

    const size_t ws_needed = (size_t)N_COLS * L_DIM * sizeof(__bf16);  // 256 KB

    if (ws_size >= ws_needed) {
        bf16x8* wf = (bf16x8*)d_ws;
        hipLaunchKernelGGL(convert_w_kernel, dim3(64), dim3(256), 0, stream, W, wf);
        hipLaunchKernelGGL(branched_policy_kernel, dim3(B_DIM / 128), dim3(256), 0, stream,
                           F, (const float4*)wf, bias, outp);
    } else {
        hipLaunchKernelGGL(fallback_kernel, dim3(B_DIM / 64), dim3(256), 0, stream,
                           F, W, bias, outp);
    }
}

// Round 11
// 40.774 us; speedup vs baseline: 1.3427x; 1.0536x over previous
//
#include <hip/hip_runtime.h>
#include <hip/hip_bf16.h>

// Problem constants
#define B_DIM   32768
#define A_DIM   64
#define L_DIM   1024          // K
#define N_COLS  128           // 2*A

using bf16x8 = __attribute__((ext_vector_type(8))) __bf16;
using f32x4  = __attribute__((ext_vector_type(4))) float;

// global -> LDS direct (16B per lane; HW: readfirstlane(base) + lane*16)
#define GLL16(g, l)                                                            \
    __builtin_amdgcn_global_load_lds(                                          \
        (const __attribute__((address_space(1))) unsigned int*)(g),            \
        (__attribute__((address_space(3))) unsigned int*)(l), 16, 0, 0)

#define VM_WAIT(n)                                                             \
    asm volatile("s_waitcnt vmcnt(" #n ")" ::: "memory");                      \
    __builtin_amdgcn_sched_barrier(0)

#define LGKM_FENCE                                                             \
    asm volatile("s_waitcnt lgkmcnt(0)" ::: "memory");                         \
    __builtin_amdgcn_sched_barrier(0)

// ---------------------------------------------------------------------------
// Pre-kernel: convert W [128 x 1024] f32 -> bf16 in MFMA B-fragment order.
// Unit v (16B): nl=v&15, sub=(v>>4)&3, cf=(v>>6)&7, ks=(v>>9)&31
//   holds Wm[n = cf*16+nl][k = ks*32 + sub*8 + i], i=0..7
// Quarter Q = ksteps [Q*8,(Q+1)*8) = units [Q*4096,(Q+1)*4096), contiguous.
// ---------------------------------------------------------------------------
__global__ __launch_bounds__(256)
void convert_w_kernel(const float* __restrict__ W, bf16x8* __restrict__ ws) {
    int v   = blockIdx.x * 256 + threadIdx.x;   // 0..16383
    int nl  = v & 15;
    int sub = (v >> 4) & 3;
    int cf  = (v >> 6) & 7;
    int ks  = (v >> 9) & 31;
    int n   = cf * 16 + nl;
    int k   = ks * 32 + sub * 8;
    const float4* wp = (const float4*)(W + (size_t)n * L_DIM + k);
    float4 w0 = wp[0];
    float4 w1 = wp[1];
    bf16x8 u;
    u[0] = (__bf16)w0.x; u[1] = (__bf16)w0.y;
    u[2] = (__bf16)w0.z; u[3] = (__bf16)w0.w;
    u[4] = (__bf16)w1.x; u[5] = (__bf16)w1.y;
    u[6] = (__bf16)w1.z; u[7] = (__bf16)w1.w;
    ws[v] = u;
}

__device__ __forceinline__ bf16x8 cvt8(float4 a, float4 b) {
    bf16x8 u;
    u[0] = (__bf16)a.x; u[1] = (__bf16)a.y; u[2] = (__bf16)a.z; u[3] = (__bf16)a.w;
    u[4] = (__bf16)b.x; u[5] = (__bf16)b.y; u[6] = (__bf16)b.z; u[7] = (__bf16)b.w;
    return u;
}

// ---------------------------------------------------------------------------
// Main kernel: 512 threads = 8 waves; wave = 16 rows x 128 cols; block =
// 128 rows; grid = 256 = 1 block/CU.
//
// A: per-wave private 5-slot LDS ring (slot = 1 kstep = 16 rows x 32 f32 =
//    2 KB = 2 GLL). Issued 5 ksteps ahead, retired by counted
//    s_waitcnt vmcnt(8) -> ~10 KB in flight per wave, 80 KB/CU, never
//    drained inside the loop. Compiler cannot sink GLL (no dest register).
//    Slot layout: GLL m (0/1), lane l=p*16+r -> float4 idx m*64+p*16+r
//    holds F[row0+r][k*32 + m*16 + p*4 ..+4). Read (r=lcol,q=lsub):
//    idx1 = (q>>1)*64 + (q&1)*32 + r, idx2 = idx1+16  (<=2-way, free).
// B: quarter-K slabs (8 ksteps, 64 KB) GLL-staged, restaged at k=8/16/24
//    (the only barriers; they also re-drain the A ring, which is harmless —
//    drained slots are already in LDS).
// ---------------------------------------------------------------------------
__global__ __launch_bounds__(512, 1)
void branched_policy_kernel(const float* __restrict__ F,
                            const float4* __restrict__ Wf,
                            const float* __restrict__ bias,
                            float* __restrict__ out) {
    __shared__ float4 ldsB[4096];        // 64 KB: current B quarter
    __shared__ float4 ldsA[8][5][128];   // 8 waves x 5-slot ring x 2 KB

    const int tid  = threadIdx.x;
    const int lane = tid & 63;
    const int wave = tid >> 6;        // 0..7
    const int blk  = blockIdx.x;
    const int lcol = lane & 15;       // fragment row (A) / col (B)
    const int lsub = lane >> 4;       // k subgroup 0..3

    const int row0 = blk * 128 + wave * 16;
    const float* fsrc = F + (size_t)(row0 + lcol) * L_DIM + lsub * 4;

#define ISSUE_A(K, S)                                                          \
    {                                                                          \
        GLL16(fsrc + (K) * 32,      &ldsA[wave][S][lane]);                     \
        GLL16(fsrc + (K) * 32 + 16, &ldsA[wave][S][64 + lane]);                \
    }

#define ISSUE_B(Q)                                                             \
    {                                                                          \
        _Pragma("unroll") for (int i = 0; i < 8; ++i)                          \
            GLL16(Wf + (Q) * 4096 + i * 512 + tid, &ldsB[i * 512 + tid]);      \
    }

    f32x4 acc[8];
    #pragma unroll
    for (int cf = 0; cf < 8; ++cf) acc[cf] = (f32x4){0.f, 0.f, 0.f, 0.f};

    // ---- prologue: B quarter 0 + A slots 0..4 ----
    ISSUE_B(0);
    ISSUE_A(0, 0); ISSUE_A(1, 1); ISSUE_A(2, 2); ISSUE_A(3, 3); ISSUE_A(4, 4);
    __syncthreads();                   // drain all: B(0) + A(0..4) resident

    #pragma unroll
    for (int k = 0; k < 32; ++k) {
        if (k == 8 || k == 16 || k == 24) {
            __syncthreads();           // all waves done reading old B quarter
            ISSUE_B(k >> 3);
            __syncthreads();           // B arrived (A ring slots already in LDS)
        }

        // wait for slot k (leave the younger slots in flight)
        if      (k < 28) { VM_WAIT(8); }
        else if (k == 28){ VM_WAIT(6); }
        else if (k == 29){ VM_WAIT(4); }
        else if (k == 30){ VM_WAIT(2); }
        else             { VM_WAIT(0); }

        // ---- compute kstep k ----
        const float4* ab = &ldsA[wave][k % 5][0];
        const int idx1 = (lsub >> 1) * 64 + (lsub & 1) * 32 + lcol;
        float4 a0 = ab[idx1];
        float4 a1 = ab[idx1 + 16];
        bf16x8 af = cvt8(a0, a1);
        #pragma unroll
        for (int cf = 0; cf < 8; ++cf) {
            bf16x8 bf = *(const bf16x8*)&ldsB[((k & 7) * 8 + cf) * 64 + lane];
            acc[cf] = __builtin_amdgcn_mfma_f32_16x16x32_bf16(af, bf, acc[cf], 0, 0, 0);
        }

        // ---- refill the slot just consumed (5 ahead) ----
        if (k + 5 < 32) {
            LGKM_FENCE;                // slot reads retired before overwrite
            ISSUE_A(k + 5, (k + 5) % 5);
        }
    }

    // ---- epilogue: bias + tanh + de-interleave ----
    float* out0 = out;
    float* out1 = out + (size_t)B_DIM * A_DIM;
    const int rowb = row0 + lsub * 4;
    #pragma unroll
    for (int cf = 0; cf < 8; ++cf) {
        int   n  = cf * 16 + lcol;
        float bv = bias[n];
        float* ob = ((n & 1) ? out1 : out0) + (n >> 1);
        #pragma unroll
        for (int j = 0; j < 4; ++j) {
            float x = acc[cf][j] + bv;
            float e = __expf(2.0f * x);               // tanh = 1 - 2/(e^2x+1)
            ob[(size_t)(rowb + j) * A_DIM] = 1.0f - 2.0f / (e + 1.0f);
        }
    }
#undef ISSUE_A
#undef ISSUE_B
}

// ---------------------------------------------------------------------------
// Fallback (v1-style, self-contained) if ws is too small.
// ---------------------------------------------------------------------------
__global__ __launch_bounds__(256, 2)
void fallback_kernel(const float* __restrict__ F,
                     const float* __restrict__ W,
                     const float* __restrict__ bias,
                     float* __restrict__ out) {
    __shared__ bf16x8 ldsB[4096];
    const int tid  = threadIdx.x;
    const int lane = tid & 63;
    const int wave = tid >> 6;
    const int blk  = blockIdx.x;
    const int lcol = lane & 15;
    const int lsub = lane >> 4;
    const int arow = blk * 64 + wave * 16 + lcol;
    const float* Fp = F + (size_t)arow * L_DIM + lsub * 8;

    f32x4 acc[8];
    #pragma unroll
    for (int c = 0; c < 8; ++c) acc[c] = (f32x4){0.f, 0.f, 0.f, 0.f};

    for (int ch = 0; ch < 4; ++ch) {
        __syncthreads();
        #pragma unroll
        for (int i = 0; i < 16; ++i) {
            int v   = i * 256 + tid;
            int nl  = v & 15;
            int sub = (v >> 4) & 3;
            int c   = (v >> 6) & 7;
            int ks  = (v >> 9) & 7;
            int nn  = c * 16 + nl;
            int k   = ch * 256 + ks * 32 + sub * 8;
            const float4* wp = (const float4*)(W + (size_t)nn * L_DIM + k);
            ldsB[v] = cvt8(wp[0], wp[1]);
        }
        __syncthreads();
        #pragma unroll
        for (int ks = 0; ks < 8; ++ks) {
            const float4* ap = (const float4*)(Fp + ch * 256 + ks * 32);
            bf16x8 af = cvt8(ap[0], ap[1]);
            #pragma unroll
            for (int c = 0; c < 8; ++c) {
                bf16x8 bf = ldsB[(ks * 8 + c) * 64 + lane];
                acc[c] = __builtin_amdgcn_mfma_f32_16x16x32_bf16(af, bf, acc[c], 0, 0, 0);
            }
        }
    }

    const int orow0 = blk * 64 + wave * 16 + lsub * 4;
    float* out0 = out;
    float* out1 = out + (size_t)B_DIM * A_DIM;
    #pragma unroll
    for (int c = 0; c < 8; ++c) {
        int   nn  = c * 16 + lcol;
        float bvv = bias[nn];
        float* ob = (nn & 1) ? out1 : out0;
        #pragma unroll
        for (int j = 0; j < 4; ++j) {
            float x = acc[c][j] + bvv;
            float e = __expf(2.0f * x);
            ob[(size_t)(orow0 + j) * A_DIM + (nn >> 1)] = 1.0f - 2.0f / (e + 1.0f);
        }
    }
}

extern "C" void kernel_launch(void* const* d_in, const int* in_sizes, int n_in,
                              void* d_out, int out_size, void* d_ws, size_t ws_size,
                              hipStream_t stream) {
    const float* F    = (const float*)d_in[0];  // [32768, 1024] f32
    const float* W    = (const float*)d_in[1];  // [64, 2, 1024] f32
    const float* bias = (const float*)d_in[2];  // [64, 2] f32
    float* outp       = (float*)d_out;          // [2][32768, 64] f32

    const size_t ws_needed = (size_t)N_COLS * L_DIM * sizeof(__bf16);  // 256 KB

    if (ws_size >= ws_needed) {
        bf16x8* wf = (bf16x8*)d_ws;
        hipLaunchKernelGGL(convert_w_kernel, dim3(64), dim3(256), 0, stream, W, wf);
        hipLaunchKernelGGL(branched_policy_kernel, dim3(B_DIM / 128), dim3(512), 0, stream,
                           F, (const float4*)wf, bias, outp);
    } else {
        hipLaunchKernelGGL(fallback_kernel, dim3(B_DIM / 64), dim3(256), 0, stream,
                           F, W, bias, outp);
    }
}